// Round 3
// baseline (230.158 us; speedup 1.0000x reference)
//
#include <hip/hip_runtime.h>
#include <math.h>

#define NB_MAX 64
#define CCHUNK 20

// accum layout (floats): [0..7]=cls_sum per batch, [8..15]=reg_sum, [16..23]=pos_cnt
// labels: int8 array B*Na at ws offset 256

__global__ void zero_kernel(float* acc) {
    if (threadIdx.x < 32) acc[threadIdx.x] = 0.f;
}

__global__ __launch_bounds__(256) void assign_kernel(
    const float* __restrict__ reg_pred,
    const float* __restrict__ annots,
    const float* __restrict__ anchors,
    signed char* __restrict__ labels,
    float* __restrict__ accum,
    int Na, int Nb)
{
    int b = blockIdx.y;
    int a = blockIdx.x * 256 + threadIdx.x;

    __shared__ float ann[NB_MAX][5];
    const float* ab = annots + b * Nb * 5;
    for (int i = threadIdx.x; i < Nb * 5; i += 256) ann[i / 5][i % 5] = ab[i];
    __syncthreads();

    float regv = 0.f, posv = 0.f;
    if (a < Na) {
        float4 anc = ((const float4*)anchors)[a];
        float ax1 = anc.x, ay1 = anc.y, ax2 = anc.z, ay2 = anc.w;
        float aw = ax2 - ax1, ah = ay2 - ay1;
        float a_area = aw * ah;

        float best = -1.f; int bestj = 0;
        for (int j = 0; j < Nb; ++j) {
            float lab = ann[j][4];
            float iou = -1.0f;
            if (lab != -1.0f) {
                float bx1 = ann[j][0], by1 = ann[j][1], bx2 = ann[j][2], by2 = ann[j][3];
                float iw = fmaxf(fminf(ax2, bx2) - fmaxf(ax1, bx1), 0.f);
                float ih = fmaxf(fminf(ay2, by2) - fmaxf(ay1, by1), 0.f);
                float inter = iw * ih;
                float b_area = (bx2 - bx1) * (by2 - by1);
                float un = fmaxf(a_area + b_area - inter, 1e-7f);
                iou = inter / un;
            }
            if (iou > best) { best = iou; bestj = j; }   // first-max kept (jnp argmax semantics)
        }

        signed char lout = -1;
        if (best >= 0.5f) {
            lout = (signed char)(int)ann[bestj][4];

            // CIoU for this positive anchor
            float r0 = reg_pred[(size_t)(b * 4 + 0) * Na + a] * 0.1f;
            float r1 = reg_pred[(size_t)(b * 4 + 1) * Na + a] * 0.1f;
            float r2 = reg_pred[(size_t)(b * 4 + 2) * Na + a] * 0.2f;
            float r3 = reg_pred[(size_t)(b * 4 + 3) * Na + a] * 0.2f;

            float acx = ax1 + 0.5f * aw, acy = ay1 + 0.5f * ah;
            float pcx = acx + r0 * aw;
            float pcy = acy + r1 * ah;
            float pw = expf(r2) * aw;
            float ph = expf(r3) * ah;

            float g0 = ann[bestj][0], g1 = ann[bestj][1];
            float g2 = ann[bestj][2], g3 = ann[bestj][3];
            float gw = fmaxf(g2 - g0, 1.0f);
            float gh = fmaxf(g3 - g1, 1.0f);
            float gcx = g0 + 0.5f * gw;
            float gcy = g1 + 0.5f * gh;

            float g_area = gw * gh, p_area = pw * ph;
            float ix1 = fmaxf(gcx - 0.5f * gw, pcx - 0.5f * pw);
            float ix2 = fminf(gcx + 0.5f * gw, pcx + 0.5f * pw);
            float iy1 = fmaxf(gcy - 0.5f * gh, pcy - 0.5f * ph);
            float iy2 = fminf(gcy + 0.5f * gh, pcy + 0.5f * ph);
            float inter = fmaxf(ix2 - ix1, 0.f) * fmaxf(iy2 - iy1, 0.f);

            float ex1 = fminf(gcx - 0.5f * gw, pcx - 0.5f * pw);
            float ex2 = fmaxf(gcx + 0.5f * gw, pcx + 0.5f * pw);
            float ey1 = fminf(gcy - 0.5f * gh, pcy - 0.5f * ph);
            float ey2 = fmaxf(gcy + 0.5f * gh, pcy + 0.5f * ph);

            float dx = gcx - pcx, dy = gcy - pcy;
            float inter_diag = dx * dx + dy * dy;
            float cdx = fmaxf(ex2 - ex1, 0.f), cdy = fmaxf(ey2 - ey1, 0.f);
            float enc_diag = cdx * cdx + cdy * cdy;

            float uni = g_area + p_area - inter;
            float u = inter_diag / fmaxf(enc_diag, 1e-6f);
            float iou = inter / fmaxf(uni, 1e-6f);
            float dv = atanf(gw / gh) - atanf(pw / ph);
            float v = (4.0f / (float)(M_PI * M_PI)) * dv * dv;
            float S = (iou > 0.5f) ? 1.f : 0.f;
            float alpha = S * v / fmaxf(1.f - iou + v, 1e-6f);
            float ciou = fminf(fmaxf(iou - u - alpha * v, -1.f), 1.f);
            regv = 1.f - ciou;
            posv = 1.f;
        }
        labels[(size_t)b * Na + a] = lout;
    }

    // block reduce (regv, posv) together
    __shared__ float s1[4], s2[4];
    #pragma unroll
    for (int off = 32; off > 0; off >>= 1) {
        regv += __shfl_down(regv, off);
        posv += __shfl_down(posv, off);
    }
    int lane = threadIdx.x & 63, wid = threadIdx.x >> 6;
    if (lane == 0) { s1[wid] = regv; s2[wid] = posv; }
    __syncthreads();
    if (threadIdx.x == 0) {
        float r = s1[0] + s1[1] + s1[2] + s1[3];
        float p = s2[0] + s2[1] + s2[2] + s2[3];
        atomicAdd(&accum[8 + b], r);
        atomicAdd(&accum[16 + b], p);
    }
}

__device__ __forceinline__ float focal1(float p, bool t) {
    p = fminf(fmaxf(p, 1e-7f), 0.99999988f);
    // t==1: 0.25*(1-p)^2*(-log p); t==0: 0.75*p^2*(-log(1-p)); unify via q
    float q = t ? p : 1.0f - p;
    float af = t ? 0.25f : 0.75f;
    float fw = 1.0f - q;
    return af * fw * fw * (-__logf(q));
}

__global__ __launch_bounds__(256) void focal_kernel(
    const float* __restrict__ cls_pred,
    const signed char* __restrict__ labels,
    float* __restrict__ accum,
    int Na, int C)
{
    int b = blockIdx.z;
    int Nq = Na >> 2;                         // Na divisible by 4
    int q = blockIdx.x * 256 + threadIdx.x;
    int c0 = blockIdx.y * CCHUNK;
    int cend = min(c0 + CCHUNK, C);

    float sum = 0.f;
    if (q < Nq) {
        char4 lab = ((const char4*)labels)[(size_t)b * Nq + q];
        int l0 = lab.x, l1 = lab.y, l2 = lab.z, l3 = lab.w;
        const float4* base = (const float4*)cls_pred + (size_t)b * C * Nq + q;
        for (int c = c0; c < cend; ++c) {
            float4 p = base[(size_t)c * Nq];
            sum += focal1(p.x, l0 == c);
            sum += focal1(p.y, l1 == c);
            sum += focal1(p.z, l2 == c);
            sum += focal1(p.w, l3 == c);
        }
    }

    __shared__ float s[4];
    #pragma unroll
    for (int off = 32; off > 0; off >>= 1) sum += __shfl_down(sum, off);
    int lane = threadIdx.x & 63, wid = threadIdx.x >> 6;
    if (lane == 0) s[wid] = sum;
    __syncthreads();
    if (threadIdx.x == 0) {
        atomicAdd(&accum[b], s[0] + s[1] + s[2] + s[3]);
    }
}

__global__ void finalize_kernel(const float* __restrict__ accum,
                                float* __restrict__ out, int B)
{
    if (threadIdx.x == 0) {
        float cs = 0.f, rs = 0.f;
        for (int b = 0; b < B; ++b) {
            float npv = accum[16 + b];
            float d = fmaxf(npv, 1.f);
            cs += accum[b] / d;
            rs += (npv > 0.f) ? accum[8 + b] / d : 0.f;
        }
        out[0] = cs / (float)B;
        out[1] = rs / (float)B;
    }
}

extern "C" void kernel_launch(void* const* d_in, const int* in_sizes, int n_in,
                              void* d_out, int out_size, void* d_ws, size_t ws_size,
                              hipStream_t stream) {
    const float* cls     = (const float*)d_in[0];
    const float* reg     = (const float*)d_in[1];
    const float* annots  = (const float*)d_in[2];
    const float* anchors = (const float*)d_in[3];

    int Na = in_sizes[3] / 4;
    int B  = in_sizes[1] / (4 * Na);
    int C  = in_sizes[0] / (B * Na);
    int Nb = in_sizes[2] / (B * 5);

    float* accum = (float*)d_ws;
    signed char* labels = (signed char*)d_ws + 256;
    float* out = (float*)d_out;

    zero_kernel<<<1, 64, 0, stream>>>(accum);

    dim3 g1((Na + 255) / 256, B);
    assign_kernel<<<g1, 256, 0, stream>>>(reg, annots, anchors, labels, accum, Na, Nb);

    int Nq = Na / 4;
    dim3 g2((Nq + 255) / 256, (C + CCHUNK - 1) / CCHUNK, B);
    focal_kernel<<<g2, 256, 0, stream>>>(cls, labels, accum, Na, C);

    finalize_kernel<<<1, 64, 0, stream>>>(accum, out, B);
}

// Round 4
// 210.666 us; speedup vs baseline: 1.0925x; 1.0925x over previous
//
#include <hip/hip_runtime.h>
#include <math.h>

#define NB_MAX 64
#define CCHUNK 10

// ws layout:
//   labels:   int8  [B*Na]                      at offset 0
//   reg_part: float [B*nblkA]                   at aligned offset
//   pos_part: float [B*nblkA]
//   cls_part: float [B*nblkF]
// Every partial slot is written by exactly one block each launch (no stale
// poison reads, no atomics, no zero-init kernel needed).

__global__ __launch_bounds__(256) void assign_kernel(
    const float* __restrict__ reg_pred,
    const float* __restrict__ annots,
    const float* __restrict__ anchors,
    signed char* __restrict__ labels,
    float* __restrict__ reg_part,
    float* __restrict__ pos_part,
    int Na, int Nb, int nblkA)
{
    int b = blockIdx.y;
    int a = blockIdx.x * 256 + threadIdx.x;

    __shared__ float ann[NB_MAX][5];
    const float* ab = annots + b * Nb * 5;
    for (int i = threadIdx.x; i < Nb * 5; i += 256) ann[i / 5][i % 5] = ab[i];
    __syncthreads();

    float regv = 0.f, posv = 0.f;
    if (a < Na) {
        float4 anc = ((const float4*)anchors)[a];
        float ax1 = anc.x, ay1 = anc.y, ax2 = anc.z, ay2 = anc.w;
        float aw = ax2 - ax1, ah = ay2 - ay1;
        float a_area = aw * ah;

        float best = -1.f; int bestj = 0;
        for (int j = 0; j < Nb; ++j) {
            float lab = ann[j][4];
            float iou = -1.0f;
            if (lab != -1.0f) {
                float bx1 = ann[j][0], by1 = ann[j][1], bx2 = ann[j][2], by2 = ann[j][3];
                float iw = fmaxf(fminf(ax2, bx2) - fmaxf(ax1, bx1), 0.f);
                float ih = fmaxf(fminf(ay2, by2) - fmaxf(ay1, by1), 0.f);
                float inter = iw * ih;
                float b_area = (bx2 - bx1) * (by2 - by1);
                float un = fmaxf(a_area + b_area - inter, 1e-7f);
                iou = inter / un;
            }
            if (iou > best) { best = iou; bestj = j; }   // first-max (jnp argmax semantics)
        }

        signed char lout = -1;
        if (best >= 0.5f) {
            lout = (signed char)(int)ann[bestj][4];

            float r0 = reg_pred[(size_t)(b * 4 + 0) * Na + a] * 0.1f;
            float r1 = reg_pred[(size_t)(b * 4 + 1) * Na + a] * 0.1f;
            float r2 = reg_pred[(size_t)(b * 4 + 2) * Na + a] * 0.2f;
            float r3 = reg_pred[(size_t)(b * 4 + 3) * Na + a] * 0.2f;

            float acx = ax1 + 0.5f * aw, acy = ay1 + 0.5f * ah;
            float pcx = acx + r0 * aw;
            float pcy = acy + r1 * ah;
            float pw = expf(r2) * aw;
            float ph = expf(r3) * ah;

            float g0 = ann[bestj][0], g1 = ann[bestj][1];
            float g2 = ann[bestj][2], g3 = ann[bestj][3];
            float gw = fmaxf(g2 - g0, 1.0f);
            float gh = fmaxf(g3 - g1, 1.0f);
            float gcx = g0 + 0.5f * gw;
            float gcy = g1 + 0.5f * gh;

            float g_area = gw * gh, p_area = pw * ph;
            float ix1 = fmaxf(gcx - 0.5f * gw, pcx - 0.5f * pw);
            float ix2 = fminf(gcx + 0.5f * gw, pcx + 0.5f * pw);
            float iy1 = fmaxf(gcy - 0.5f * gh, pcy - 0.5f * ph);
            float iy2 = fminf(gcy + 0.5f * gh, pcy + 0.5f * ph);
            float inter = fmaxf(ix2 - ix1, 0.f) * fmaxf(iy2 - iy1, 0.f);

            float ex1 = fminf(gcx - 0.5f * gw, pcx - 0.5f * pw);
            float ex2 = fmaxf(gcx + 0.5f * gw, pcx + 0.5f * pw);
            float ey1 = fminf(gcy - 0.5f * gh, pcy - 0.5f * ph);
            float ey2 = fmaxf(gcy + 0.5f * gh, pcy + 0.5f * ph);

            float dx = gcx - pcx, dy = gcy - pcy;
            float inter_diag = dx * dx + dy * dy;
            float cdx = fmaxf(ex2 - ex1, 0.f), cdy = fmaxf(ey2 - ey1, 0.f);
            float enc_diag = cdx * cdx + cdy * cdy;

            float uni = g_area + p_area - inter;
            float u = inter_diag / fmaxf(enc_diag, 1e-6f);
            float iou = inter / fmaxf(uni, 1e-6f);
            float dv = atanf(gw / gh) - atanf(pw / ph);
            float v = (4.0f / (float)(M_PI * M_PI)) * dv * dv;
            float S = (iou > 0.5f) ? 1.f : 0.f;
            float alpha = S * v / fmaxf(1.f - iou + v, 1e-6f);
            float ciou = fminf(fmaxf(iou - u - alpha * v, -1.f), 1.f);
            regv = 1.f - ciou;
            posv = 1.f;
        }
        labels[(size_t)b * Na + a] = lout;
    }

    __shared__ float s1[4], s2[4];
    #pragma unroll
    for (int off = 32; off > 0; off >>= 1) {
        regv += __shfl_down(regv, off);
        posv += __shfl_down(posv, off);
    }
    int lane = threadIdx.x & 63, wid = threadIdx.x >> 6;
    if (lane == 0) { s1[wid] = regv; s2[wid] = posv; }
    __syncthreads();
    if (threadIdx.x == 0) {
        reg_part[(size_t)b * nblkA + blockIdx.x] = s1[0] + s1[1] + s1[2] + s1[3];
        pos_part[(size_t)b * nblkA + blockIdx.x] = s2[0] + s2[1] + s2[2] + s2[3];
    }
}

__device__ __forceinline__ float focal1(float p, bool t) {
    p = fminf(fmaxf(p, 1e-7f), 0.99999988f);
    float q = t ? p : 1.0f - p;
    float af = t ? 0.25f : 0.75f;
    float fw = 1.0f - q;
    return af * fw * fw * (-__logf(q));
}

__global__ __launch_bounds__(256) void focal_kernel(
    const float* __restrict__ cls_pred,
    const signed char* __restrict__ labels,
    float* __restrict__ cls_part,
    int Na, int C, int nchunk, int nblkF)
{
    int b = blockIdx.z;
    int No = Na >> 3;                       // 8 anchors per thread (Na % 8 == 0)
    int Nq = Na >> 2;
    int q = blockIdx.x * 256 + threadIdx.x;
    int c0 = blockIdx.y * CCHUNK;
    int cend = min(c0 + CCHUNK, C);

    float sum = 0.f;
    if (q < No) {
        const char4* lp = (const char4*)(labels + (size_t)b * Na) + 2 * q;
        char4 la = lp[0], lb = lp[1];
        int l0 = la.x, l1 = la.y, l2 = la.z, l3 = la.w;
        int l4 = lb.x, l5 = lb.y, l6 = lb.z, l7 = lb.w;
        const float4* base = (const float4*)cls_pred + (size_t)b * C * Nq + 2 * q;
        for (int c = c0; c < cend; ++c) {
            float4 p0 = base[(size_t)c * Nq];
            float4 p1 = base[(size_t)c * Nq + 1];
            sum += focal1(p0.x, l0 == c);
            sum += focal1(p0.y, l1 == c);
            sum += focal1(p0.z, l2 == c);
            sum += focal1(p0.w, l3 == c);
            sum += focal1(p1.x, l4 == c);
            sum += focal1(p1.y, l5 == c);
            sum += focal1(p1.z, l6 == c);
            sum += focal1(p1.w, l7 == c);
        }
    }

    __shared__ float s[4];
    #pragma unroll
    for (int off = 32; off > 0; off >>= 1) sum += __shfl_down(sum, off);
    int lane = threadIdx.x & 63, wid = threadIdx.x >> 6;
    if (lane == 0) s[wid] = sum;
    __syncthreads();
    if (threadIdx.x == 0) {
        cls_part[(size_t)b * nblkF + blockIdx.x * nchunk + blockIdx.y] =
            s[0] + s[1] + s[2] + s[3];
    }
}

__global__ __launch_bounds__(512) void finalize_kernel(
    const float* __restrict__ reg_part,
    const float* __restrict__ pos_part,
    const float* __restrict__ cls_part,
    float* __restrict__ out,
    int B, int nblkA, int nblkF)
{
    int w = threadIdx.x >> 6;      // wave id = batch id
    int lane = threadIdx.x & 63;

    float cs = 0.f, rs = 0.f, ps = 0.f;
    if (w < B) {
        for (int i = lane; i < nblkA; i += 64) {
            rs += reg_part[(size_t)w * nblkA + i];
            ps += pos_part[(size_t)w * nblkA + i];
        }
        for (int i = lane; i < nblkF; i += 64) {
            cs += cls_part[(size_t)w * nblkF + i];
        }
    }
    #pragma unroll
    for (int off = 32; off > 0; off >>= 1) {
        cs += __shfl_down(cs, off);
        rs += __shfl_down(rs, off);
        ps += __shfl_down(ps, off);
    }
    __shared__ float sc[8], sr[8];
    if (w < B && lane == 0) {
        float d = fmaxf(ps, 1.f);
        sc[w] = cs / d;
        sr[w] = (ps > 0.f) ? rs / d : 0.f;
    }
    __syncthreads();
    if (threadIdx.x == 0) {
        float a = 0.f, r = 0.f;
        for (int i = 0; i < B; ++i) { a += sc[i]; r += sr[i]; }
        out[0] = a / (float)B;
        out[1] = r / (float)B;
    }
}

extern "C" void kernel_launch(void* const* d_in, const int* in_sizes, int n_in,
                              void* d_out, int out_size, void* d_ws, size_t ws_size,
                              hipStream_t stream) {
    const float* cls     = (const float*)d_in[0];
    const float* reg     = (const float*)d_in[1];
    const float* annots  = (const float*)d_in[2];
    const float* anchors = (const float*)d_in[3];

    int Na = in_sizes[3] / 4;
    int B  = in_sizes[1] / (4 * Na);
    int C  = in_sizes[0] / (B * Na);
    int Nb = in_sizes[2] / (B * 5);

    int nblkA  = (Na + 255) / 256;
    int No     = Na / 8;
    int nblkX  = (No + 255) / 256;
    int nchunk = (C + CCHUNK - 1) / CCHUNK;
    int nblkF  = nblkX * nchunk;

    signed char* labels = (signed char*)d_ws;
    size_t off = ((size_t)B * Na + 255) & ~(size_t)255;
    float* reg_part = (float*)((char*)d_ws + off);
    float* pos_part = reg_part + (size_t)B * nblkA;
    float* cls_part = pos_part + (size_t)B * nblkA;
    float* out = (float*)d_out;

    dim3 g1(nblkA, B);
    assign_kernel<<<g1, 256, 0, stream>>>(reg, annots, anchors, labels,
                                          reg_part, pos_part, Na, Nb, nblkA);

    dim3 g2(nblkX, nchunk, B);
    focal_kernel<<<g2, 256, 0, stream>>>(cls, labels, cls_part, Na, C, nchunk, nblkF);

    finalize_kernel<<<1, 512, 0, stream>>>(reg_part, pos_part, cls_part, out,
                                           B, nblkA, nblkF);
}

// Round 5
// 205.232 us; speedup vs baseline: 1.1215x; 1.0265x over previous
//
#include <hip/hip_runtime.h>
#include <math.h>

#define NB_MAX 64

// ws layout (floats): cls_part[B*nblk], reg_part[B*nblk], pos_part[B*nblk]
// each slot written by exactly one block per launch (no stale poison reads,
// no atomics, no zero-init).

__device__ __forceinline__ float focal1(float p, bool t) {
    p = fminf(fmaxf(p, 1e-7f), 0.99999988f);
    float q = t ? p : 1.0f - p;      // t==1: p ;  t==0: 1-p
    float af = t ? 0.25f : 0.75f;
    float fw = 1.0f - q;
    return af * fw * fw * (-__logf(q));
}

__global__ __launch_bounds__(256) void fused_kernel(
    const float* __restrict__ cls_pred,
    const float* __restrict__ reg_pred,
    const float* __restrict__ annots,
    const float* __restrict__ anchors,
    float* __restrict__ cls_part,
    float* __restrict__ reg_part,
    float* __restrict__ pos_part,
    int Na, int Nb, int C, int nblk)
{
    int b = blockIdx.y;
    int h = blockIdx.x * 256 + threadIdx.x;   // pair index: anchors 2h, 2h+1
    int Nh = Na >> 1;

    __shared__ float ann[NB_MAX][5];
    const float* ab = annots + b * Nb * 5;
    for (int i = threadIdx.x; i < Nb * 5; i += 256) ann[i / 5][i % 5] = ab[i];
    __syncthreads();

    float clsv = 0.f, regv = 0.f, posv = 0.f;
    int lab[2] = {-1, -1};

    if (h < Nh) {
        // ---- assignment + CIoU for the two owned anchors (all in registers)
        #pragma unroll
        for (int s = 0; s < 2; ++s) {
            int a = 2 * h + s;
            float4 anc = ((const float4*)anchors)[a];
            float ax1 = anc.x, ay1 = anc.y, ax2 = anc.z, ay2 = anc.w;
            float aw = ax2 - ax1, ah = ay2 - ay1;
            float a_area = aw * ah;

            float best = -1.f; int bestj = 0;
            for (int j = 0; j < Nb; ++j) {
                float labj = ann[j][4];
                float iou = -1.0f;
                if (labj != -1.0f) {
                    float bx1 = ann[j][0], by1 = ann[j][1];
                    float bx2 = ann[j][2], by2 = ann[j][3];
                    float iw = fmaxf(fminf(ax2, bx2) - fmaxf(ax1, bx1), 0.f);
                    float ih = fmaxf(fminf(ay2, by2) - fmaxf(ay1, by1), 0.f);
                    float inter = iw * ih;
                    float b_area = (bx2 - bx1) * (by2 - by1);
                    float un = fmaxf(a_area + b_area - inter, 1e-7f);
                    iou = inter / un;
                }
                if (iou > best) { best = iou; bestj = j; }  // first-max (jnp argmax)
            }

            if (best >= 0.5f) {
                lab[s] = (int)ann[bestj][4];

                float r0 = reg_pred[(size_t)(b * 4 + 0) * Na + a] * 0.1f;
                float r1 = reg_pred[(size_t)(b * 4 + 1) * Na + a] * 0.1f;
                float r2 = reg_pred[(size_t)(b * 4 + 2) * Na + a] * 0.2f;
                float r3 = reg_pred[(size_t)(b * 4 + 3) * Na + a] * 0.2f;

                float acx = ax1 + 0.5f * aw, acy = ay1 + 0.5f * ah;
                float pcx = acx + r0 * aw;
                float pcy = acy + r1 * ah;
                float pw = expf(r2) * aw;
                float ph = expf(r3) * ah;

                float g0 = ann[bestj][0], g1 = ann[bestj][1];
                float g2 = ann[bestj][2], g3 = ann[bestj][3];
                float gw = fmaxf(g2 - g0, 1.0f);
                float gh = fmaxf(g3 - g1, 1.0f);
                float gcx = g0 + 0.5f * gw;
                float gcy = g1 + 0.5f * gh;

                float g_area = gw * gh, p_area = pw * ph;
                float ix1 = fmaxf(gcx - 0.5f * gw, pcx - 0.5f * pw);
                float ix2 = fminf(gcx + 0.5f * gw, pcx + 0.5f * pw);
                float iy1 = fmaxf(gcy - 0.5f * gh, pcy - 0.5f * ph);
                float iy2 = fminf(gcy + 0.5f * gh, pcy + 0.5f * ph);
                float inter = fmaxf(ix2 - ix1, 0.f) * fmaxf(iy2 - iy1, 0.f);

                float ex1 = fminf(gcx - 0.5f * gw, pcx - 0.5f * pw);
                float ex2 = fmaxf(gcx + 0.5f * gw, pcx + 0.5f * pw);
                float ey1 = fminf(gcy - 0.5f * gh, pcy - 0.5f * ph);
                float ey2 = fmaxf(gcy + 0.5f * gh, pcy + 0.5f * ph);

                float dx = gcx - pcx, dy = gcy - pcy;
                float inter_diag = dx * dx + dy * dy;
                float cdx = fmaxf(ex2 - ex1, 0.f), cdy = fmaxf(ey2 - ey1, 0.f);
                float enc_diag = cdx * cdx + cdy * cdy;

                float uni = g_area + p_area - inter;
                float u = inter_diag / fmaxf(enc_diag, 1e-6f);
                float iou = inter / fmaxf(uni, 1e-6f);
                float dv = atanf(gw / gh) - atanf(pw / ph);
                float v = (4.0f / (float)(M_PI * M_PI)) * dv * dv;
                float S = (iou > 0.5f) ? 1.f : 0.f;
                float alpha = S * v / fmaxf(1.f - iou + v, 1e-6f);
                float ciou = fminf(fmaxf(iou - u - alpha * v, -1.f), 1.f);
                regv += 1.f - ciou;
                posv += 1.f;
            }
        }

        // ---- focal over all classes, coalesced float2 stream
        int l0 = lab[0], l1 = lab[1];
        const float2* base = (const float2*)cls_pred + (size_t)b * C * Nh + h;
        #pragma unroll 4
        for (int c = 0; c < C; ++c) {
            float2 p = base[(size_t)c * Nh];
            clsv += focal1(p.x, l0 == c);
            clsv += focal1(p.y, l1 == c);
        }
    }

    // ---- block reduce (clsv, regv, posv)
    __shared__ float s1[4], s2[4], s3[4];
    #pragma unroll
    for (int off = 32; off > 0; off >>= 1) {
        clsv += __shfl_down(clsv, off);
        regv += __shfl_down(regv, off);
        posv += __shfl_down(posv, off);
    }
    int lane = threadIdx.x & 63, wid = threadIdx.x >> 6;
    if (lane == 0) { s1[wid] = clsv; s2[wid] = regv; s3[wid] = posv; }
    __syncthreads();
    if (threadIdx.x == 0) {
        size_t slot = (size_t)b * nblk + blockIdx.x;
        cls_part[slot] = s1[0] + s1[1] + s1[2] + s1[3];
        reg_part[slot] = s2[0] + s2[1] + s2[2] + s2[3];
        pos_part[slot] = s3[0] + s3[1] + s3[2] + s3[3];
    }
}

__global__ __launch_bounds__(512) void finalize_kernel(
    const float* __restrict__ cls_part,
    const float* __restrict__ reg_part,
    const float* __restrict__ pos_part,
    float* __restrict__ out,
    int B, int nblk)
{
    int w = threadIdx.x >> 6;      // wave id = batch id
    int lane = threadIdx.x & 63;

    float cs = 0.f, rs = 0.f, ps = 0.f;
    if (w < B) {
        for (int i = lane; i < nblk; i += 64) {
            cs += cls_part[(size_t)w * nblk + i];
            rs += reg_part[(size_t)w * nblk + i];
            ps += pos_part[(size_t)w * nblk + i];
        }
    }
    #pragma unroll
    for (int off = 32; off > 0; off >>= 1) {
        cs += __shfl_down(cs, off);
        rs += __shfl_down(rs, off);
        ps += __shfl_down(ps, off);
    }
    __shared__ float sc[8], sr[8];
    if (w < B && lane == 0) {
        float d = fmaxf(ps, 1.f);
        sc[w] = cs / d;
        sr[w] = (ps > 0.f) ? rs / d : 0.f;
    }
    __syncthreads();
    if (threadIdx.x == 0) {
        float a = 0.f, r = 0.f;
        for (int i = 0; i < B; ++i) { a += sc[i]; r += sr[i]; }
        out[0] = a / (float)B;
        out[1] = r / (float)B;
    }
}

extern "C" void kernel_launch(void* const* d_in, const int* in_sizes, int n_in,
                              void* d_out, int out_size, void* d_ws, size_t ws_size,
                              hipStream_t stream) {
    const float* cls     = (const float*)d_in[0];
    const float* reg     = (const float*)d_in[1];
    const float* annots  = (const float*)d_in[2];
    const float* anchors = (const float*)d_in[3];

    int Na = in_sizes[3] / 4;
    int B  = in_sizes[1] / (4 * Na);
    int C  = in_sizes[0] / (B * Na);
    int Nb = in_sizes[2] / (B * 5);

    int Nh   = Na / 2;
    int nblk = (Nh + 255) / 256;

    float* cls_part = (float*)d_ws;
    float* reg_part = cls_part + (size_t)B * nblk;
    float* pos_part = reg_part + (size_t)B * nblk;
    float* out = (float*)d_out;

    dim3 g1(nblk, B);
    fused_kernel<<<g1, 256, 0, stream>>>(cls, reg, annots, anchors,
                                         cls_part, reg_part, pos_part,
                                         Na, Nb, C, nblk);

    finalize_kernel<<<1, 512, 0, stream>>>(cls_part, reg_part, pos_part, out,
                                           B, nblk);
}